// Round 8
// baseline (313.639 us; speedup 1.0000x reference)
//
#include <hip/hip_runtime.h>
#include <hip/hip_bf16.h>
#include <stdint.h>

#define D_MODEL 1024
#define NUM_HEADS 16
#define DK 64
#define BATCH 4
#define SEQ 2048
#define MTOT (BATCH * SEQ)   // 8192 tokens

typedef unsigned short u16;
typedef unsigned int u32;
typedef __bf16 bf16x8 __attribute__((ext_vector_type(8)));
typedef float f32x4 __attribute__((ext_vector_type(4)));
typedef short s16x4 __attribute__((ext_vector_type(4)));
typedef int   i32x4 __attribute__((ext_vector_type(4)));
typedef int   i32x2 __attribute__((ext_vector_type(2)));
typedef uint  u32x2 __attribute__((ext_vector_type(2)));

// v_mfma_f32_16x16x16_bf16 (gfx90a+ "_1k" builtin name): A,B = 2 VGPRs (4 bf16), C/D = 4.
__device__ __forceinline__ f32x4 mfma16(s16x4 a, s16x4 b, f32x4 c) {
  return __builtin_amdgcn_mfma_f32_16x16x16bf16_1k(a, b, c, 0, 0, 0);
}

__device__ __forceinline__ u16 f2bf(float f) {
  union { float f; unsigned u; } c; c.f = f;
  unsigned u = c.u + 0x7fffu + ((c.u >> 16) & 1u);   // RNE
  return (u16)(u >> 16);
}
// pack two f32 into bf16x2 (truncate) — 1 instr
__device__ __forceinline__ u32 pack_bf2(float f0, float f1) {
  return __builtin_amdgcn_perm(__float_as_uint(f1), __float_as_uint(f0), 0x07060302u);
}
__device__ __forceinline__ s16x4 cast_s16x4(u32 lo, u32 hi) {
  u32x2 t = {lo, hi};
  return (s16x4)t;
}

// async global->LDS, 16B per lane (GEMM staging; LDS dst contiguous per wave).
__device__ __forceinline__ void async16(void* g, void* lds) {
  __builtin_amdgcn_global_load_lds(
      (__attribute__((address_space(1))) void*)g,
      (__attribute__((address_space(3))) void*)lds,
      16, 0, 0);
}

// ---------------- f32 -> bf16, all 7 tensors in one dispatch ----------------
struct CvtArgs {
  const float* s[7];
  u16* d[7];
  int n[7];
};
__global__ __launch_bounds__(256)
void cvt_multi(CvtArgs a) {
  const int which = blockIdx.y;
  const int n = a.n[which];
  const int i = (blockIdx.x * 256 + threadIdx.x) * 8;
  if (i >= n) return;
  const float* s = a.s[which];
  u16* d = a.d[which];
  const float4 x = *(const float4*)(s + i);
  const float4 y = *(const float4*)(s + i + 4);
  *(ushort4*)(d + i)     = make_ushort4(f2bf(x.x), f2bf(x.y), f2bf(x.z), f2bf(x.w));
  *(ushort4*)(d + i + 4) = make_ushort4(f2bf(y.x), f2bf(y.y), f2bf(y.z), f2bf(y.w));
}

// ---------------- GEMM: C = (A @ W^T + bias) * oscale -----------------------
// 128x128 tile, BK=32, 4-BUFFER LDS pipeline, counted vmcnt(8) (T4): iter c
// stages chunk c+3, computes chunk c, waits only until chunk c+1 landed —
// 2 full chunks stay in flight across the barrier (round 7 kept 1, MfmaUtil
// 29%). LDS 4x16KB = 64KB; at 512 blocks/dispatch = 2 blocks/CU the extra
// buffer costs no occupancy (measured 26% = 2/CU already).
// UNBATCHED (one dispatch per tensor) this round: with the batched 73µs
// dispatch split into ~24µs pieces, the next profile's top-5 must surface
// the attn/cvt/out-proj durations — ~120µs/iter is currently invisible
// below the top-5 cutoff and must be located before further optimization.
// MODE 0: C bf16 [M,1024].  MODE 2: C f32 [M,1024].
// MODE 1 (VT): C -> VtX[b*1024+chan][SEQ] bf16, key dim chunk-interleaved:
//   within each 32-key chunk, key kt*16+qd*4+j stored at pos qd*8+kt*4+j.
template <int MODE>
__global__ __launch_bounds__(256, 2)
void gemm_bt_bias(const u16* __restrict__ A, const u16* __restrict__ W,
                  const float* __restrict__ bias, void* __restrict__ Cv,
                  float oscale)
{
  __shared__ __align__(16) u16 smem[32768];   // 4 x (As 4096 + Bs 4096) u16
  const int t = threadIdx.x;
  const int w = t >> 6, l = t & 63;
  const int quad = l >> 4, lane16 = l & 15;
  const int m0 = blockIdx.x * 128;
  const int n0 = blockIdx.y * 128;
  const int wm = (w >> 1) * 64, wn = (w & 1) * 64;

  const int srow = t >> 2;
  const int scol = (t & 3) * 8;
  const u16* Ag = A + (long)(m0 + srow) * D_MODEL + scol;
  const u16* Wg = W + (long)(n0 + srow) * D_MODEL + scol;

  f32x4 acc[4][4] = {};

  auto stage = [&](int buf, int k0) {
    u16* As_ = smem + buf * 8192;
    u16* Bs_ = As_ + 4096;
    async16((void*)(Ag + k0), As_ + w * 512);
    async16((void*)(Ag + 64 * D_MODEL + k0), As_ + w * 512 + 2048);
    async16((void*)(Wg + k0), Bs_ + w * 512);
    async16((void*)(Wg + 64 * D_MODEL + k0), Bs_ + w * 512 + 2048);
  };
  auto compute = [&](int buf) {
    const u16* As_ = smem + buf * 8192;
    const u16* Bs_ = As_ + 4096;
    bf16x8 af[4], bfr[4];
#pragma unroll
    for (int i = 0; i < 4; ++i)
      af[i] = *(const bf16x8*)&As_[(wm + i * 16 + lane16) * 32 + quad * 8];
#pragma unroll
    for (int i = 0; i < 4; ++i)
      bfr[i] = *(const bf16x8*)&Bs_[(wn + i * 16 + lane16) * 32 + quad * 8];
#pragma unroll
    for (int i = 0; i < 4; ++i)
#pragma unroll
      for (int jn = 0; jn < 4; ++jn)
        acc[i][jn] = __builtin_amdgcn_mfma_f32_16x16x32_bf16(af[i], bfr[jn], acc[i][jn], 0, 0, 0);
  };

  // prologue: chunks 0,1,2 in flight (12 loads); wait chunk 0 (leave 8)
  stage(0, 0);
  stage(1, 32);
  stage(2, 64);
  asm volatile("s_waitcnt vmcnt(8)" ::: "memory");
  __builtin_amdgcn_s_barrier();
  __builtin_amdgcn_sched_barrier(0);

  int buf = 0;
#pragma unroll 1
  for (int c = 0; c < 32; ++c) {
    if (c + 3 < 32) stage((buf + 3) & 3, (c + 3) * 32);
    compute(buf);
    if (c < 31) {
      // need chunk c+1 landed; chunks c+2..min(c+3,31) may stay in flight
      if (c <= 28)      asm volatile("s_waitcnt vmcnt(8)" ::: "memory");
      else if (c == 29) asm volatile("s_waitcnt vmcnt(4)" ::: "memory");
      else              asm volatile("s_waitcnt vmcnt(0)" ::: "memory");
      __builtin_amdgcn_s_barrier();
      __builtin_amdgcn_sched_barrier(0);
    }
    buf = (buf + 1) & 3;
  }
  __syncthreads();   // all waves done reading smem before T union / exit

  if constexpr (MODE == 1) {
    // restage through LDS (reuses smem — main loop done): T[dk][key], pad 132
    u16* T = smem;
#pragma unroll
    for (int jn = 0; jn < 4; ++jn) {
      const int col = wn + jn * 16 + lane16;          // dk_local
      const float bb = bias[n0 + col];
#pragma unroll
      for (int i = 0; i < 4; ++i) {
        const int rbase = wm + i * 16 + quad * 4;     // key_local
#pragma unroll
        for (int r = 0; r < 4; ++r)
          T[col * 132 + rbase + r] = f2bf((acc[i][jn][r] + bb) * oscale);
      }
    }
    __syncthreads();
    // coalesced, chunk-interleaved writeout: out pos 4a..4a+3 <- keys
    // (a>>3)*32 + ((a&7)>>1)*4 + (a&1)*16 + {0..3}
    const int bq = m0 >> 11, sbase = m0 & 2047;
    const int a = t & 31;
    const int keystart = ((a >> 3) * 32) + (((a & 7) >> 1) * 4) + ((a & 1) * 16);
    u16* orow = (u16*)Cv + ((long)bq * 1024 + n0) * SEQ + sbase + 4 * a;
#pragma unroll
    for (int pass = 0; pass < 16; ++pass) {
      const int dkl = (t >> 5) + 8 * pass;
      *(u32x2*)(orow + (long)dkl * SEQ) = *(const u32x2*)&T[dkl * 132 + keystart];
    }
  } else {
#pragma unroll
    for (int jn = 0; jn < 4; ++jn) {
      const int col = n0 + wn + jn * 16 + lane16;
      const float bb = bias[col];
#pragma unroll
      for (int i = 0; i < 4; ++i) {
        const int rbase = m0 + wm + i * 16 + quad * 4;
#pragma unroll
        for (int r = 0; r < 4; ++r) {
          const float v = (acc[i][jn][r] + bb) * oscale;
          if (MODE == 2) ((float*)Cv)[(long)(rbase + r) * D_MODEL + col] = v;
          else           ((u16*)Cv)[(long)(rbase + r) * D_MODEL + col] = f2bf(v);
        }
      }
    }
  }
}

// ---------------- Causal flash attention: LDS-staged K/V, 4 strips/block ----
// (byte-identical to rounds 6/7 — held fixed for clean attribution)
__global__ __launch_bounds__(256, 3)
void attn_causal(const u16* __restrict__ Q, const u16* __restrict__ K,
                 const u16* __restrict__ VtX, u16* __restrict__ O)
{
  __shared__ __align__(16) u16 Kb[2][32][64];   // 8KB, swizzled
  __shared__ __align__(16) u16 Vb[2][64][32];   // 8KB, swizzled
  const int t = threadIdx.x;
  const int w = t >> 6, l = t & 63;
  const int quad = l >> 4, lane16 = l & 15;

  const int lin = blockIdx.x;        // 0..1023
  const int xcd = lin & 7;
  const int j = lin >> 3;            // 0..127
  const int bh = xcd * 8 + (j & 7);  // same bh -> same XCD (id%8 round-robin)
  const int g = 15 - (j >> 3);       // 0..15, heavy blocks first
  const int b = bh >> 4, h = bh & 15;
  const int sw = 4 * g + w;          // this wave's strip (32 q-rows)
  const int cmax = 4 * g + 3;        // last chunk any wave in block needs
  const int qbase = sw * 32;

  const long qkbase = (long)b * SEQ * D_MODEL + h * DK;

  // Q B-frags (x32): lane(q=lane16, quad) holds Q[q][ks*32+quad*8 ..+7]
  bf16x8 qf[2][2];
#pragma unroll
  for (int qi = 0; qi < 2; ++qi)
#pragma unroll
    for (int ks = 0; ks < 2; ++ks)
      qf[qi][ks] = *(const bf16x8*)&Q[qkbase +
          (long)(qbase + qi * 16 + lane16) * D_MODEL + ks * 32 + quad * 8];

  // staging addresses: K chunk = 32 rows x 128B slice; V chunk = 64 rows x 64B
  const int krow = t >> 3, kc = t & 7;          // 256 thr: 32 rows x 8 units
  const char* Kgt = (const char*)(K + qkbase) + (long)krow * (D_MODEL * 2) + kc * 16;
  u16* KbD0 = &Kb[0][krow][(kc ^ (krow & 7)) * 8];
  u16* KbD1 = &Kb[1][krow][(kc ^ (krow & 7)) * 8];
  const int vrow = t >> 2, vc = t & 3;          // 256 thr: 64 rows x 4 units
  const char* Vgt = (const char*)(VtX + ((long)b * 1024 + h * 64) * SEQ) +
                    (long)vrow * (SEQ * 2) + vc * 16;
  u16* VbD0 = &Vb[0][vrow][(vc ^ (vrow & 3)) * 8];
  u16* VbD1 = &Vb[1][vrow][(vc ^ (vrow & 3)) * 8];

  f32x4 oacc[4][2] = {};     // [d][qi], O^T tiles for this wave's strip
  float lsum[2] = {0.f, 0.f};

  auto body = [&](const u16 (*Kbuf)[64], const u16 (*Vbuf)[32], bool diag) {
    // K A-frags from LDS (swizzled): lane(key=lane16, quad)
    bf16x8 kf[2][2];
#pragma unroll
    for (int kt = 0; kt < 2; ++kt)
#pragma unroll
      for (int ks = 0; ks < 2; ++ks)
        kf[kt][ks] = *(const bf16x8*)
            &Kbuf[kt * 16 + lane16][(((ks * 4 + quad) ^ (lane16 & 7)) * 8)];
    // Vt A-frags from LDS (swizzled)
    i32x4 vfd[4];
#pragma unroll
    for (int d = 0; d < 4; ++d)
      vfd[d] = *(const i32x4*)
          &Vbuf[d * 16 + lane16][((quad ^ (lane16 & 3)) * 8)];

    // S^T = K·Q^T  (Q pre-scaled; result is log2-domain score)
    f32x4 st[2][2] = {};     // [kt][qi]
    __builtin_amdgcn_s_setprio(1);
#pragma unroll
    for (int kt = 0; kt < 2; ++kt)
#pragma unroll
      for (int qi = 0; qi < 2; ++qi)
#pragma unroll
        for (int ks = 0; ks < 2; ++ks)
          st[kt][qi] = __builtin_amdgcn_mfma_f32_16x16x32_bf16(kf[kt][ks], qf[qi][ks], st[kt][qi], 0, 0, 0);
    __builtin_amdgcn_s_setprio(0);

    // exp2 (raw v_exp_f32), causal mask only on the peeled diagonal chunk
    u32 pb[2][2][2];         // [kt][qi][pair]
#pragma unroll
    for (int kt = 0; kt < 2; ++kt)
#pragma unroll
      for (int qi = 0; qi < 2; ++qi) {
        float pv[4];
#pragma unroll
        for (int r = 0; r < 4; ++r) {
          float p = __builtin_amdgcn_exp2f(st[kt][qi][r]);
          if (diag && (kt * 16 + quad * 4 + r > qi * 16 + lane16)) p = 0.f;
          pv[r] = p;
        }
        lsum[qi] += (pv[0] + pv[1]) + (pv[2] + pv[3]);
        pb[kt][qi][0] = pack_bf2(pv[0], pv[1]);
        pb[kt][qi][1] = pack_bf2(pv[2], pv[3]);
      }

    // O^T += Vt·P^T  (x16; P^T B-frag = packed scores, layout identity)
    __builtin_amdgcn_s_setprio(1);
#pragma unroll
    for (int d = 0; d < 4; ++d) {
      const s16x4 va0 = cast_s16x4((u32)vfd[d].x, (u32)vfd[d].y);
      const s16x4 va1 = cast_s16x4((u32)vfd[d].z, (u32)vfd[d].w);
#pragma unroll
      for (int qi = 0; qi < 2; ++qi) {
        const s16x4 pb0 = cast_s16x4(pb[0][qi][0], pb[0][qi][1]);
        const s16x4 pb1 = cast_s16x4(pb[1][qi][0], pb[1][qi][1]);
        oacc[d][qi] = mfma16(va0, pb0, oacc[d][qi]);
        oacc[d][qi] = mfma16(va1, pb1, oacc[d][qi]);
      }
    }
    __builtin_amdgcn_s_setprio(0);
  };

  // ---- staged chunk loop (chunks 0..cmax, count = 4(g+1), even) ----
  // K chunk byte stride: 32 rows * 2048B = 65536; V chunk byte stride: 64.
  {
    // prologue: stage chunk 0, prefetch chunks 1,2 into regs
    i32x4 a0 = *(const i32x4*)(Kgt);
    i32x4 a1 = *(const i32x4*)(Vgt);
    *(i32x4*)KbD0 = a0;
    *(i32x4*)VbD0 = a1;
  }
  i32x4 gKA = *(const i32x4*)(Kgt + 65536);
  i32x4 gVA = *(const i32x4*)(Vgt + 64);
  i32x4 gKB = *(const i32x4*)(Kgt + 2 * 65536);
  i32x4 gVB = *(const i32x4*)(Vgt + 2 * 64);
  __syncthreads();

  for (int c = 0; c <= cmax; c += 2) {
    // state: buf0 = chunk c (ready); gA = c+1; gB = c+2 (if exists)
    *(i32x4*)KbD1 = gKA;
    *(i32x4*)VbD1 = gVA;
    if (c + 3 <= cmax) {
      gKA = *(const i32x4*)(Kgt + (long)(c + 3) * 65536);
      gVA = *(const i32x4*)(Vgt + (long)(c + 3) * 64);
    }
    if (c <= sw) body(Kb[0], Vb[0], c == sw);
    __syncthreads();                  // buf1 (chunk c+1) ready
    if (c + 2 <= cmax) {
      *(i32x4*)KbD0 = gKB;
      *(i32x4*)VbD0 = gVB;
      if (c + 4 <= cmax) {
        gKB = *(const i32x4*)(Kgt + (long)(c + 4) * 65536);
        gVB = *(const i32x4*)(Vgt + (long)(c + 4) * 64);
      }
    }
    if (c + 1 <= sw) body(Kb[1], Vb[1], (c + 1) == sw);
    __syncthreads();                  // buf0 (chunk c+2) ready
  }

  // ---- softmax denominator: reduce lsum across quads, then epilogue ----
  float linv[2];
#pragma unroll
  for (int qi = 0; qi < 2; ++qi) {
    float v = lsum[qi];
    v += __shfl_xor(v, 16);
    v += __shfl_xor(v, 32);
    linv[qi] = 1.f / v;
  }

  // epilogue: O[q][dk] = oacc^T / l ; lane writes 4 consecutive dk as b64
#pragma unroll
  for (int qi = 0; qi < 2; ++qi) {
    const long row = (long)b * SEQ + qbase + qi * 16 + lane16;
#pragma unroll
    for (int d = 0; d < 4; ++d) {
      const u32 p0 = ((u32)f2bf(oacc[d][qi][0] * linv[qi])) |
                     ((u32)f2bf(oacc[d][qi][1] * linv[qi]) << 16);
      const u32 p1 = ((u32)f2bf(oacc[d][qi][2] * linv[qi])) |
                     ((u32)f2bf(oacc[d][qi][3] * linv[qi]) << 16);
      u32x2 pk = {p0, p1};
      *(u32x2*)&O[row * D_MODEL + h * 64 + d * 16 + quad * 4] = pk;
    }
  }
}

extern "C" void kernel_launch(void* const* d_in, const int* in_sizes, int n_in,
                              void* d_out, int out_size, void* d_ws, size_t ws_size,
                              hipStream_t stream) {
  const float* q  = (const float*)d_in[0];
  const float* k  = (const float*)d_in[1];
  const float* v  = (const float*)d_in[2];
  // d_in[3]: causal mask (tril) — semantics hardcoded in attn_causal
  const float* Wq = (const float*)d_in[4];
  const float* bq = (const float*)d_in[5];
  const float* Wk = (const float*)d_in[6];
  const float* bk = (const float*)d_in[7];
  const float* Wv = (const float*)d_in[8];
  const float* bv = (const float*)d_in[9];
  const float* Wo = (const float*)d_in[10];
  const float* bo = (const float*)d_in[11];
  float* out = (float*)d_out;

  const size_t NT = (size_t)MTOT * D_MODEL;
  const size_t NW = (size_t)D_MODEL * D_MODEL;

  u16* w0  = (u16*)d_ws;
  u16* qb  = w0;
  u16* kb  = w0 + NT;
  u16* vb  = w0 + 2 * NT;
  u16* Wqb = w0 + 3 * NT;
  u16* Wkb = Wqb + NW;
  u16* Wvb = Wqb + 2 * NW;
  u16* Wob = Wqb + 3 * NW;
  u16* Qp  = (u16*)d_out;        // d_out doubles as bf16 scratch until final GEMM
  u16* Kp  = (u16*)d_out + NT;
  u16* Vpt = qb;                 // qb dead after GEMM1 (VtX layout)
  u16* Xp  = kb;                 // kb dead after GEMM2

  const dim3 blk(256);

  CvtArgs ca;
  ca.s[0] = q;  ca.d[0] = qb;  ca.n[0] = (int)NT;
  ca.s[1] = k;  ca.d[1] = kb;  ca.n[1] = (int)NT;
  ca.s[2] = v;  ca.d[2] = vb;  ca.n[2] = (int)NT;
  ca.s[3] = Wq; ca.d[3] = Wqb; ca.n[3] = (int)NW;
  ca.s[4] = Wk; ca.d[4] = Wkb; ca.n[4] = (int)NW;
  ca.s[5] = Wv; ca.d[5] = Wvb; ca.n[5] = (int)NW;
  ca.s[6] = Wo; ca.d[6] = Wob; ca.n[6] = (int)NW;
  cvt_multi<<<dim3(4096, 7), blk, 0, stream>>>(ca);

  const float SC = 0.125f * 1.4426950408889634f;   // 1/sqrt(dk) * log2(e)
  const dim3 ggrid(MTOT / 128, D_MODEL / 128);

  gemm_bt_bias<0><<<ggrid, blk, 0, stream>>>(qb, Wqb, bq, Qp,  SC);
  gemm_bt_bias<0><<<ggrid, blk, 0, stream>>>(kb, Wkb, bk, Kp,  1.f);
  gemm_bt_bias<1><<<ggrid, blk, 0, stream>>>(vb, Wvb, bv, Vpt, 1.f);

  const dim3 agrid(1024);
  attn_causal<<<agrid, blk, 0, stream>>>(Qp, Kp, Vpt, Xp);

  gemm_bt_bias<2><<<ggrid, blk, 0, stream>>>(Xp, Wob, bo, out, 1.f);
}

// Round 9
// 307.140 us; speedup vs baseline: 1.0212x; 1.0212x over previous
//
#include <hip/hip_runtime.h>
#include <hip/hip_bf16.h>
#include <stdint.h>

#define D_MODEL 1024
#define NUM_HEADS 16
#define DK 64
#define BATCH 4
#define SEQ 2048
#define MTOT (BATCH * SEQ)   // 8192 tokens

typedef unsigned short u16;
typedef unsigned int u32;
typedef __bf16 bf16x8 __attribute__((ext_vector_type(8)));
typedef float f32x4 __attribute__((ext_vector_type(4)));
typedef short s16x4 __attribute__((ext_vector_type(4)));
typedef int   i32x4 __attribute__((ext_vector_type(4)));
typedef int   i32x2 __attribute__((ext_vector_type(2)));
typedef uint  u32x2 __attribute__((ext_vector_type(2)));

// v_mfma_f32_16x16x16_bf16 (gfx90a+ "_1k" builtin name): A,B = 2 VGPRs (4 bf16), C/D = 4.
__device__ __forceinline__ f32x4 mfma16(s16x4 a, s16x4 b, f32x4 c) {
  return __builtin_amdgcn_mfma_f32_16x16x16bf16_1k(a, b, c, 0, 0, 0);
}

__device__ __forceinline__ u16 f2bf(float f) {
  union { float f; unsigned u; } c; c.f = f;
  unsigned u = c.u + 0x7fffu + ((c.u >> 16) & 1u);   // RNE
  return (u16)(u >> 16);
}
// pack two f32 into bf16x2 (truncate) — 1 instr
__device__ __forceinline__ u32 pack_bf2(float f0, float f1) {
  return __builtin_amdgcn_perm(__float_as_uint(f1), __float_as_uint(f0), 0x07060302u);
}
__device__ __forceinline__ s16x4 cast_s16x4(u32 lo, u32 hi) {
  u32x2 t = {lo, hi};
  return (s16x4)t;
}

// async global->LDS, 16B per lane (GEMM staging; LDS dst contiguous per wave).
__device__ __forceinline__ void async16(void* g, void* lds) {
  __builtin_amdgcn_global_load_lds(
      (__attribute__((address_space(1))) void*)g,
      (__attribute__((address_space(3))) void*)lds,
      16, 0, 0);
}

// ---------------- f32 -> bf16, all 7 tensors in one dispatch ----------------
struct CvtArgs {
  const float* s[7];
  u16* d[7];
  int n[7];
};
__global__ __launch_bounds__(256)
void cvt_multi(CvtArgs a) {
  const int which = blockIdx.y;
  const int n = a.n[which];
  const int i = (blockIdx.x * 256 + threadIdx.x) * 8;
  if (i >= n) return;
  const float* s = a.s[which];
  u16* d = a.d[which];
  const float4 x = *(const float4*)(s + i);
  const float4 y = *(const float4*)(s + i + 4);
  *(ushort4*)(d + i)     = make_ushort4(f2bf(x.x), f2bf(x.y), f2bf(x.z), f2bf(x.w));
  *(ushort4*)(d + i + 4) = make_ushort4(f2bf(y.x), f2bf(y.y), f2bf(y.z), f2bf(y.w));
}

// ---------------- GEMM: C = (A @ W^T + bias) * oscale -----------------------
// ROUND-7-PROVEN config restored (73.5µs for batched QKV): 128x128 tile,
// BK=32, 3-buffer LDS pipeline, counted vmcnt(4) — iter c stages chunk c+2,
// computes c, waits only for chunk c+1 (c+2 stays in flight across the
// barrier). Round-8's unbatched 512-block dispatches regressed ~2x (inferred
// ~50µs each): no block-refill to cover pipeline fill/drain at 2-3 resident
// blocks/CU. BATCHED grid.z=3 (QKV in one 1536-block dispatch) restored.
// NEW this round: T5 s_setprio(1) around the 16-MFMA cluster — the counted
// vmcnt pipeline has wave role diversity (stage-issuing vs MFMA-entering),
// the regime where setprio pays (m218b/m224); null risk otherwise.
// LDS: 3 x 16KB = 48KB; VT restage T (33KB) unions over smem post-loop.
// mode 0: C bf16 [M,1024].  mode 2: C f32 [M,1024].
// mode 1 (VT): C -> VtX[b*1024+chan][SEQ] bf16, key dim chunk-interleaved:
//   within each 32-key chunk, key kt*16+qd*4+j stored at pos qd*8+kt*4+j.
struct GBatch {
  const u16* A[3]; const u16* W[3]; const float* bias[3];
  void* C[3]; float osc[3]; int mode[3];
};
__global__ __launch_bounds__(256, 2)
void gemm_bt_bias(GBatch ga)
{
  __shared__ __align__(16) u16 smem[24576];   // 3 x (As 4096 + Bs 4096) u16
  const int z = blockIdx.z;
  const u16* __restrict__ A = ga.A[z];
  const u16* __restrict__ W = ga.W[z];
  const float* __restrict__ bias = ga.bias[z];
  void* __restrict__ Cv = ga.C[z];
  const float oscale = ga.osc[z];
  const int mode = ga.mode[z];

  const int t = threadIdx.x;
  const int w = t >> 6, l = t & 63;
  const int quad = l >> 4, lane16 = l & 15;
  const int m0 = blockIdx.x * 128;
  const int n0 = blockIdx.y * 128;
  const int wm = (w >> 1) * 64, wn = (w & 1) * 64;

  const int srow = t >> 2;
  const int scol = (t & 3) * 8;
  const u16* Ag = A + (long)(m0 + srow) * D_MODEL + scol;
  const u16* Wg = W + (long)(n0 + srow) * D_MODEL + scol;

  f32x4 acc[4][4] = {};

  auto stage = [&](int buf, int k0) {
    u16* As_ = smem + buf * 8192;
    u16* Bs_ = As_ + 4096;
    async16((void*)(Ag + k0), As_ + w * 512);
    async16((void*)(Ag + 64 * D_MODEL + k0), As_ + w * 512 + 2048);
    async16((void*)(Wg + k0), Bs_ + w * 512);
    async16((void*)(Wg + 64 * D_MODEL + k0), Bs_ + w * 512 + 2048);
  };
  auto compute = [&](int buf) {
    const u16* As_ = smem + buf * 8192;
    const u16* Bs_ = As_ + 4096;
    bf16x8 af[4], bfr[4];
#pragma unroll
    for (int i = 0; i < 4; ++i)
      af[i] = *(const bf16x8*)&As_[(wm + i * 16 + lane16) * 32 + quad * 8];
#pragma unroll
    for (int i = 0; i < 4; ++i)
      bfr[i] = *(const bf16x8*)&Bs_[(wn + i * 16 + lane16) * 32 + quad * 8];
    __builtin_amdgcn_s_setprio(1);
#pragma unroll
    for (int i = 0; i < 4; ++i)
#pragma unroll
      for (int jn = 0; jn < 4; ++jn)
        acc[i][jn] = __builtin_amdgcn_mfma_f32_16x16x32_bf16(af[i], bfr[jn], acc[i][jn], 0, 0, 0);
    __builtin_amdgcn_s_setprio(0);
  };

  // prologue: chunks 0,1 in flight; wait chunk 0 (leave chunk 1's 4 loads)
  stage(0, 0);
  stage(1, 32);
  asm volatile("s_waitcnt vmcnt(4)" ::: "memory");
  __builtin_amdgcn_s_barrier();
  __builtin_amdgcn_sched_barrier(0);

  int buf = 0;
#pragma unroll 1
  for (int c = 0; c < 32; ++c) {
    if (c + 2 < 32) stage((buf + 2 >= 3) ? buf - 1 : buf + 2, (c + 2) * 32);
    compute(buf);
    if (c < 30) {
      asm volatile("s_waitcnt vmcnt(4)" ::: "memory");   // chunk c+1 landed
      __builtin_amdgcn_s_barrier();
      __builtin_amdgcn_sched_barrier(0);
    } else if (c == 30) {
      asm volatile("s_waitcnt vmcnt(0)" ::: "memory");   // tail: chunk 31
      __builtin_amdgcn_s_barrier();
      __builtin_amdgcn_sched_barrier(0);
    }
    buf = (buf + 1 == 3) ? 0 : buf + 1;
  }
  __syncthreads();   // all waves done reading smem before T union / exit

  if (mode == 1) {
    // restage through LDS (reuses smem — main loop done): T[dk][key], pad 132
    u16* T = smem;
#pragma unroll
    for (int jn = 0; jn < 4; ++jn) {
      const int col = wn + jn * 16 + lane16;          // dk_local
      const float bb = bias[n0 + col];
#pragma unroll
      for (int i = 0; i < 4; ++i) {
        const int rbase = wm + i * 16 + quad * 4;     // key_local
#pragma unroll
        for (int r = 0; r < 4; ++r)
          T[col * 132 + rbase + r] = f2bf((acc[i][jn][r] + bb) * oscale);
      }
    }
    __syncthreads();
    // coalesced, chunk-interleaved writeout: out pos 4a..4a+3 <- keys
    // (a>>3)*32 + ((a&7)>>1)*4 + (a&1)*16 + {0..3}
    const int bq = m0 >> 11, sbase = m0 & 2047;
    const int a = t & 31;
    const int keystart = ((a >> 3) * 32) + (((a & 7) >> 1) * 4) + ((a & 1) * 16);
    u16* orow = (u16*)Cv + ((long)bq * 1024 + n0) * SEQ + sbase + 4 * a;
#pragma unroll
    for (int pass = 0; pass < 16; ++pass) {
      const int dkl = (t >> 5) + 8 * pass;
      *(u32x2*)(orow + (long)dkl * SEQ) = *(const u32x2*)&T[dkl * 132 + keystart];
    }
  } else {
#pragma unroll
    for (int jn = 0; jn < 4; ++jn) {
      const int col = n0 + wn + jn * 16 + lane16;
      const float bb = bias[col];
#pragma unroll
      for (int i = 0; i < 4; ++i) {
        const int rbase = m0 + wm + i * 16 + quad * 4;
#pragma unroll
        for (int r = 0; r < 4; ++r) {
          const float v = (acc[i][jn][r] + bb) * oscale;
          if (mode == 2) ((float*)Cv)[(long)(rbase + r) * D_MODEL + col] = v;
          else           ((u16*)Cv)[(long)(rbase + r) * D_MODEL + col] = f2bf(v);
        }
      }
    }
  }
}

// ---------------- Causal flash attention: LDS-staged K/V, 4 strips/block ----
// (byte-identical to rounds 6/7/8 — held fixed for clean attribution)
__global__ __launch_bounds__(256, 3)
void attn_causal(const u16* __restrict__ Q, const u16* __restrict__ K,
                 const u16* __restrict__ VtX, u16* __restrict__ O)
{
  __shared__ __align__(16) u16 Kb[2][32][64];   // 8KB, swizzled
  __shared__ __align__(16) u16 Vb[2][64][32];   // 8KB, swizzled
  const int t = threadIdx.x;
  const int w = t >> 6, l = t & 63;
  const int quad = l >> 4, lane16 = l & 15;

  const int lin = blockIdx.x;        // 0..1023
  const int xcd = lin & 7;
  const int j = lin >> 3;            // 0..127
  const int bh = xcd * 8 + (j & 7);  // same bh -> same XCD (id%8 round-robin)
  const int g = 15 - (j >> 3);       // 0..15, heavy blocks first
  const int b = bh >> 4, h = bh & 15;
  const int sw = 4 * g + w;          // this wave's strip (32 q-rows)
  const int cmax = 4 * g + 3;        // last chunk any wave in block needs
  const int qbase = sw * 32;

  const long qkbase = (long)b * SEQ * D_MODEL + h * DK;

  // Q B-frags (x32): lane(q=lane16, quad) holds Q[q][ks*32+quad*8 ..+7]
  bf16x8 qf[2][2];
#pragma unroll
  for (int qi = 0; qi < 2; ++qi)
#pragma unroll
    for (int ks = 0; ks < 2; ++ks)
      qf[qi][ks] = *(const bf16x8*)&Q[qkbase +
          (long)(qbase + qi * 16 + lane16) * D_MODEL + ks * 32 + quad * 8];

  // staging addresses: K chunk = 32 rows x 128B slice; V chunk = 64 rows x 64B
  const int krow = t >> 3, kc = t & 7;          // 256 thr: 32 rows x 8 units
  const char* Kgt = (const char*)(K + qkbase) + (long)krow * (D_MODEL * 2) + kc * 16;
  u16* KbD0 = &Kb[0][krow][(kc ^ (krow & 7)) * 8];
  u16* KbD1 = &Kb[1][krow][(kc ^ (krow & 7)) * 8];
  const int vrow = t >> 2, vc = t & 3;          // 256 thr: 64 rows x 4 units
  const char* Vgt = (const char*)(VtX + ((long)b * 1024 + h * 64) * SEQ) +
                    (long)vrow * (SEQ * 2) + vc * 16;
  u16* VbD0 = &Vb[0][vrow][(vc ^ (vrow & 3)) * 8];
  u16* VbD1 = &Vb[1][vrow][(vc ^ (vrow & 3)) * 8];

  f32x4 oacc[4][2] = {};     // [d][qi], O^T tiles for this wave's strip
  float lsum[2] = {0.f, 0.f};

  auto body = [&](const u16 (*Kbuf)[64], const u16 (*Vbuf)[32], bool diag) {
    // K A-frags from LDS (swizzled): lane(key=lane16, quad)
    bf16x8 kf[2][2];
#pragma unroll
    for (int kt = 0; kt < 2; ++kt)
#pragma unroll
      for (int ks = 0; ks < 2; ++ks)
        kf[kt][ks] = *(const bf16x8*)
            &Kbuf[kt * 16 + lane16][(((ks * 4 + quad) ^ (lane16 & 7)) * 8)];
    // Vt A-frags from LDS (swizzled)
    i32x4 vfd[4];
#pragma unroll
    for (int d = 0; d < 4; ++d)
      vfd[d] = *(const i32x4*)
          &Vbuf[d * 16 + lane16][((quad ^ (lane16 & 3)) * 8)];

    // S^T = K·Q^T  (Q pre-scaled; result is log2-domain score)
    f32x4 st[2][2] = {};     // [kt][qi]
    __builtin_amdgcn_s_setprio(1);
#pragma unroll
    for (int kt = 0; kt < 2; ++kt)
#pragma unroll
      for (int qi = 0; qi < 2; ++qi)
#pragma unroll
        for (int ks = 0; ks < 2; ++ks)
          st[kt][qi] = __builtin_amdgcn_mfma_f32_16x16x32_bf16(kf[kt][ks], qf[qi][ks], st[kt][qi], 0, 0, 0);
    __builtin_amdgcn_s_setprio(0);

    // exp2 (raw v_exp_f32), causal mask only on the peeled diagonal chunk
    u32 pb[2][2][2];         // [kt][qi][pair]
#pragma unroll
    for (int kt = 0; kt < 2; ++kt)
#pragma unroll
      for (int qi = 0; qi < 2; ++qi) {
        float pv[4];
#pragma unroll
        for (int r = 0; r < 4; ++r) {
          float p = __builtin_amdgcn_exp2f(st[kt][qi][r]);
          if (diag && (kt * 16 + quad * 4 + r > qi * 16 + lane16)) p = 0.f;
          pv[r] = p;
        }
        lsum[qi] += (pv[0] + pv[1]) + (pv[2] + pv[3]);
        pb[kt][qi][0] = pack_bf2(pv[0], pv[1]);
        pb[kt][qi][1] = pack_bf2(pv[2], pv[3]);
      }

    // O^T += Vt·P^T  (x16; P^T B-frag = packed scores, layout identity)
    __builtin_amdgcn_s_setprio(1);
#pragma unroll
    for (int d = 0; d < 4; ++d) {
      const s16x4 va0 = cast_s16x4((u32)vfd[d].x, (u32)vfd[d].y);
      const s16x4 va1 = cast_s16x4((u32)vfd[d].z, (u32)vfd[d].w);
#pragma unroll
      for (int qi = 0; qi < 2; ++qi) {
        const s16x4 pb0 = cast_s16x4(pb[0][qi][0], pb[0][qi][1]);
        const s16x4 pb1 = cast_s16x4(pb[1][qi][0], pb[1][qi][1]);
        oacc[d][qi] = mfma16(va0, pb0, oacc[d][qi]);
        oacc[d][qi] = mfma16(va1, pb1, oacc[d][qi]);
      }
    }
    __builtin_amdgcn_s_setprio(0);
  };

  // ---- staged chunk loop (chunks 0..cmax, count = 4(g+1), even) ----
  // K chunk byte stride: 32 rows * 2048B = 65536; V chunk byte stride: 64.
  {
    // prologue: stage chunk 0, prefetch chunks 1,2 into regs
    i32x4 a0 = *(const i32x4*)(Kgt);
    i32x4 a1 = *(const i32x4*)(Vgt);
    *(i32x4*)KbD0 = a0;
    *(i32x4*)VbD0 = a1;
  }
  i32x4 gKA = *(const i32x4*)(Kgt + 65536);
  i32x4 gVA = *(const i32x4*)(Vgt + 64);
  i32x4 gKB = *(const i32x4*)(Kgt + 2 * 65536);
  i32x4 gVB = *(const i32x4*)(Vgt + 2 * 64);
  __syncthreads();

  for (int c = 0; c <= cmax; c += 2) {
    // state: buf0 = chunk c (ready); gA = c+1; gB = c+2 (if exists)
    *(i32x4*)KbD1 = gKA;
    *(i32x4*)VbD1 = gVA;
    if (c + 3 <= cmax) {
      gKA = *(const i32x4*)(Kgt + (long)(c + 3) * 65536);
      gVA = *(const i32x4*)(Vgt + (long)(c + 3) * 64);
    }
    if (c <= sw) body(Kb[0], Vb[0], c == sw);
    __syncthreads();                  // buf1 (chunk c+1) ready
    if (c + 2 <= cmax) {
      *(i32x4*)KbD0 = gKB;
      *(i32x4*)VbD0 = gVB;
      if (c + 4 <= cmax) {
        gKB = *(const i32x4*)(Kgt + (long)(c + 4) * 65536);
        gVB = *(const i32x4*)(Vgt + (long)(c + 4) * 64);
      }
    }
    if (c + 1 <= sw) body(Kb[1], Vb[1], (c + 1) == sw);
    __syncthreads();                  // buf0 (chunk c+2) ready
  }

  // ---- softmax denominator: reduce lsum across quads, then epilogue ----
  float linv[2];
#pragma unroll
  for (int qi = 0; qi < 2; ++qi) {
    float v = lsum[qi];
    v += __shfl_xor(v, 16);
    v += __shfl_xor(v, 32);
    linv[qi] = 1.f / v;
  }

  // epilogue: O[q][dk] = oacc^T / l ; lane writes 4 consecutive dk as b64
#pragma unroll
  for (int qi = 0; qi < 2; ++qi) {
    const long row = (long)b * SEQ + qbase + qi * 16 + lane16;
#pragma unroll
    for (int d = 0; d < 4; ++d) {
      const u32 p0 = ((u32)f2bf(oacc[d][qi][0] * linv[qi])) |
                     ((u32)f2bf(oacc[d][qi][1] * linv[qi]) << 16);
      const u32 p1 = ((u32)f2bf(oacc[d][qi][2] * linv[qi])) |
                     ((u32)f2bf(oacc[d][qi][3] * linv[qi]) << 16);
      u32x2 pk = {p0, p1};
      *(u32x2*)&O[row * D_MODEL + h * 64 + d * 16 + quad * 4] = pk;
    }
  }
}

extern "C" void kernel_launch(void* const* d_in, const int* in_sizes, int n_in,
                              void* d_out, int out_size, void* d_ws, size_t ws_size,
                              hipStream_t stream) {
  const float* q  = (const float*)d_in[0];
  const float* k  = (const float*)d_in[1];
  const float* v  = (const float*)d_in[2];
  // d_in[3]: causal mask (tril) — semantics hardcoded in attn_causal
  const float* Wq = (const float*)d_in[4];
  const float* bq = (const float*)d_in[5];
  const float* Wk = (const float*)d_in[6];
  const float* bk = (const float*)d_in[7];
  const float* Wv = (const float*)d_in[8];
  const float* bv = (const float*)d_in[9];
  const float* Wo = (const float*)d_in[10];
  const float* bo = (const float*)d_in[11];
  float* out = (float*)d_out;

  const size_t NT = (size_t)MTOT * D_MODEL;
  const size_t NW = (size_t)D_MODEL * D_MODEL;

  u16* w0  = (u16*)d_ws;
  u16* qb  = w0;
  u16* kb  = w0 + NT;
  u16* vb  = w0 + 2 * NT;
  u16* Wqb = w0 + 3 * NT;
  u16* Wkb = Wqb + NW;
  u16* Wvb = Wqb + 2 * NW;
  u16* Wob = Wqb + 3 * NW;
  u16* Qp  = (u16*)d_out;        // d_out doubles as bf16 scratch until final GEMM
  u16* Kp  = (u16*)d_out + NT;
  u16* Vpt = qb;                 // qb dead after GEMM1 (VtX layout)
  u16* Xp  = kb;                 // kb dead after GEMM2

  const dim3 blk(256);

  CvtArgs ca;
  ca.s[0] = q;  ca.d[0] = qb;  ca.n[0] = (int)NT;
  ca.s[1] = k;  ca.d[1] = kb;  ca.n[1] = (int)NT;
  ca.s[2] = v;  ca.d[2] = vb;  ca.n[2] = (int)NT;
  ca.s[3] = Wq; ca.d[3] = Wqb; ca.n[3] = (int)NW;
  ca.s[4] = Wk; ca.d[4] = Wkb; ca.n[4] = (int)NW;
  ca.s[5] = Wv; ca.d[5] = Wvb; ca.n[5] = (int)NW;
  ca.s[6] = Wo; ca.d[6] = Wob; ca.n[6] = (int)NW;
  cvt_multi<<<dim3(4096, 7), blk, 0, stream>>>(ca);

  const float SC = 0.125f * 1.4426950408889634f;   // 1/sqrt(dk) * log2(e)

  // QKV projections, one batched dispatch (z = 0,1,2; z=2 is the VT layout)
  GBatch g1;
  g1.A[0] = qb; g1.W[0] = Wqb; g1.bias[0] = bq; g1.C[0] = Qp;  g1.osc[0] = SC;  g1.mode[0] = 0;
  g1.A[1] = kb; g1.W[1] = Wkb; g1.bias[1] = bk; g1.C[1] = Kp;  g1.osc[1] = 1.f; g1.mode[1] = 0;
  g1.A[2] = vb; g1.W[2] = Wvb; g1.bias[2] = bv; g1.C[2] = Vpt; g1.osc[2] = 1.f; g1.mode[2] = 1;
  gemm_bt_bias<<<dim3(MTOT / 128, D_MODEL / 128, 3), blk, 0, stream>>>(g1);

  const dim3 agrid(1024);
  attn_causal<<<agrid, blk, 0, stream>>>(Qp, Kp, Vpt, Xp);

  // output projection (f32 out); only z=0 used
  GBatch g2;
  for (int i = 0; i < 3; ++i) {
    g2.A[i] = Xp; g2.W[i] = Wob; g2.bias[i] = bo; g2.C[i] = out;
    g2.osc[i] = 1.f; g2.mode[i] = 2;
  }
  gemm_bt_bias<<<dim3(MTOT / 128, D_MODEL / 128, 1), blk, 0, stream>>>(g2);
}